// Round 3
// baseline (460.683 us; speedup 1.0000x reference)
//
#include <hip/hip_runtime.h>
#include <math.h>

#define NR 8192
#define DIM 1024

typedef __attribute__((ext_vector_type(8))) short bf16x8;
typedef __attribute__((ext_vector_type(4))) float f32x4;

static __device__ __forceinline__ unsigned short f2bf(float f) {
  unsigned int u = __float_as_uint(f);
  u += 0x7fffu + ((u >> 16) & 1u);   // round-to-nearest-even
  return (unsigned short)(u >> 16);
}

static __device__ __forceinline__ float bf2f(unsigned short u) {
  return __uint_as_float(((unsigned int)u) << 16);
}

static __device__ __forceinline__ void gload_lds16(const void* g, void* lds) {
  __builtin_amdgcn_global_load_lds(
      (const __attribute__((address_space(1))) unsigned int*)g,
      (__attribute__((address_space(3))) unsigned int*)lds, 16, 0, 0);
}

// ---------------- zero-init for diag / L accumulators ----------------
__global__ __launch_bounds__(256) void zerok(float* __restrict__ p, int n) {
  int i = blockIdx.x * 256 + threadIdx.x;
  if (i < n) p[i] = 0.0f;
}

// ---------------- fp32 -> bf16 convert (vectorized) ----------------
__global__ __launch_bounds__(256) void cvt_bf16(const float* __restrict__ in,
                                                unsigned short* __restrict__ outp,
                                                int n4) {
  int i = blockIdx.x * 256 + threadIdx.x;
  if (i < n4) {
    float4 v = ((const float4*)in)[i];
    ushort4 o;
    o.x = f2bf(v.x); o.y = f2bf(v.y); o.z = f2bf(v.z); o.w = f2bf(v.w);
    ((ushort4*)outp)[i] = o;
  }
}

// ---------------- shared 128x128 bf16 NT GEMM core (m97 structure) ----------------
// A[M][K] row-major bf16, B[N][K] row-major bf16 (computes A * B^T).
static __device__ __forceinline__ void gemm_core(const unsigned short* A,
                                                 const unsigned short* B,
                                                 int m0, int n0, int K,
                                                 short* As, short* Bs,
                                                 f32x4 acc[4][4]) {
  const int tid  = threadIdx.x;
  const int lane = tid & 63;
  const int wave = tid >> 6;
  const int wr = wave >> 1, wc = wave & 1;
  const int ch_r = lane >> 2;        // row within a 16-row staging chunk
  const int ch_c = (lane & 3) * 8;   // bf16-element k offset within row

  for (int kt = 0; kt < K; kt += 32) {
#pragma unroll
    for (int c = 0; c < 4; ++c) {
      int ch = wave * 4 + c;
      if (ch < 8) {
        const unsigned short* g = A + (size_t)(m0 + ch * 16 + ch_r) * DIM + kt + ch_c;
        gload_lds16(g, As + ch * 512);
      } else {
        const unsigned short* g = B + (size_t)(n0 + (ch - 8) * 16 + ch_r) * DIM + kt + ch_c;
        gload_lds16(g, Bs + (ch - 8) * 512);
      }
    }
    asm volatile("s_waitcnt vmcnt(0)" ::: "memory");
    __syncthreads();

    bf16x8 af[4], bfr[4];
#pragma unroll
    for (int m = 0; m < 4; ++m)
      af[m] = *(const bf16x8*)(As + (wr * 64 + m * 16 + (lane & 15)) * 32 + (lane >> 4) * 8);
#pragma unroll
    for (int n = 0; n < 4; ++n)
      bfr[n] = *(const bf16x8*)(Bs + (wc * 64 + n * 16 + (lane & 15)) * 32 + (lane >> 4) * 8);
#pragma unroll
    for (int m = 0; m < 4; ++m)
#pragma unroll
      for (int n = 0; n < 4; ++n)
        acc[m][n] = __builtin_amdgcn_mfma_f32_16x16x32_bf16(af[m], bfr[n], acc[m][n], 0, 0, 0);
    __syncthreads();
  }
}

// ---------------- GEMM1: xp = relu(x @ W^T + b), bf16 out + diag atomics --------
__global__ __launch_bounds__(256) void gemm1_relu(const unsigned short* __restrict__ Xb,
                                                  const unsigned short* __restrict__ Wb,
                                                  const float* __restrict__ bias,
                                                  unsigned short* __restrict__ XP,
                                                  float* __restrict__ diag) {
  __shared__ short As[4096], Bs[4096];
  const int m0 = blockIdx.y * 128, n0 = blockIdx.x * 128;
  f32x4 acc[4][4] = {};
  gemm_core(Xb, Wb, m0, n0, DIM, As, Bs, acc);

  const int lane = threadIdx.x & 63, wave = threadIdx.x >> 6;
  const int wr = wave >> 1, wc = wave & 1, g = lane >> 4, li = lane & 15;
  float bv[4];
#pragma unroll
  for (int n = 0; n < 4; ++n) bv[n] = bias[n0 + wc * 64 + n * 16 + li];
#pragma unroll
  for (int m = 0; m < 4; ++m) {
#pragma unroll
    for (int r = 0; r < 4; ++r) {
      int row = m0 + wr * 64 + m * 16 + g * 4 + r;
      float ds = 0.0f;
#pragma unroll
      for (int n = 0; n < 4; ++n) {
        int col = n0 + wc * 64 + n * 16 + li;
        float v = fmaxf(acc[m][n][r] + bv[n], 0.0f);
        XP[(size_t)row * DIM + col] = f2bf(v);
        ds += v * v;
      }
#pragma unroll
      for (int off = 1; off < 16; off <<= 1) ds += __shfl_xor(ds, off);
      if (li == 0) atomicAdd(&diag[row], ds);
    }
  }
}

// ---------------- GEMM2: P = exp(s - diag_row) bf16, L via atomics ----------------
// Packed lower-triangle grid (2080 blocks), XCD-swizzled.
__global__ __launch_bounds__(256) void gemm2_scores(const unsigned short* __restrict__ XP,
                                                    const float* __restrict__ rwp,
                                                    unsigned short* __restrict__ Pb,
                                                    const float* __restrict__ diag,
                                                    float* __restrict__ Lrow) {
  // XCD swizzle: nwg = 2080, 2080 % 8 == 0 -> bijective simple form
  int t = ((int)blockIdx.x & 7) * 260 + ((int)blockIdx.x >> 3);
  // triangular decode: t = by*(by+1)/2 + bx, bx <= by
  int by = (int)((sqrtf(8.0f * (float)t + 1.0f) - 1.0f) * 0.5f);
  while ((by + 1) * (by + 2) / 2 <= t) ++by;
  while (by * (by + 1) / 2 > t) --by;
  const int bx = t - by * (by + 1) / 2;

  __shared__ short As[4096], Bs[4096];
  const int m0 = by * 128, n0 = bx * 128;
  f32x4 acc[4][4] = {};
  gemm_core(XP, XP, m0, n0, DIM, As, Bs, acc);

  const float rw = rwp[0];
  const int lane = threadIdx.x & 63, wave = threadIdx.x >> 6;
  const int wr = wave >> 1, wc = wave & 1, g = lane >> 4, li = lane & 15;

#pragma unroll
  for (int m = 0; m < 4; ++m) {
#pragma unroll
    for (int r = 0; r < 4; ++r) {
      const int row = m0 + wr * 64 + m * 16 + g * 4 + r;
      const float dg = diag[row];
      float se = 0.0f;
#pragma unroll
      for (int n = 0; n < 4; ++n) {
        int col = n0 + wc * 64 + n * 16 + li;
        float v = acc[m][n][r];
        v = (col <= row) ? v + rw * (float)(row - col) : -INFINITY;
        float e = __expf(v - dg);        // masked: exp(-inf) = 0
        se += e;
        if (col <= row) Pb[(size_t)row * NR + col] = f2bf(e);
      }
#pragma unroll
      for (int off = 1; off < 16; off <<= 1) se += __shfl_xor(se, off);
      if (li == 0) atomicAdd(&Lrow[row], se);
    }
  }
}

// ---------------- normalize: out = P * rcp(L[row]) (lower), 0 (upper) ----------
__global__ __launch_bounds__(256) void normk(const unsigned short* __restrict__ Pb,
                                             float* __restrict__ out,
                                             const float* __restrict__ Lrow) {
  const size_t idx = (size_t)blockIdx.x * 256 + threadIdx.x;  // float4 index
  const int row = (int)(idx >> 11);      // 2048 float4 per row
  const int j0 = (int)(idx & 2047) * 4;
  float4* p = (float4*)out + idx;
  if (j0 > row) {
    float4 z; z.x = 0.f; z.y = 0.f; z.z = 0.f; z.w = 0.f;
    *p = z;
    return;
  }
  const float sc = __builtin_amdgcn_rcpf(Lrow[row]);
  ushort4 q = *(const ushort4*)(Pb + (size_t)row * NR + j0);
  float4 o;
  o.x = bf2f(q.x) * sc;
  o.y = bf2f(q.y) * sc;
  o.z = bf2f(q.z) * sc;
  o.w = bf2f(q.w) * sc;
  if (j0 + 3 > row) {               // boundary quad: zero the masked tail
    if (j0 + 1 > row) o.y = 0.f;
    if (j0 + 2 > row) o.z = 0.f;
    o.w = 0.f;
  }
  *p = o;
}

extern "C" void kernel_launch(void* const* d_in, const int* in_sizes, int n_in,
                              void* d_out, int out_size, void* d_ws, size_t ws_size,
                              hipStream_t stream) {
  const float* x  = (const float*)d_in[0];
  const float* W  = (const float*)d_in[1];
  const float* b  = (const float*)d_in[2];
  const float* rw = (const float*)d_in[3];
  float* out = (float*)d_out;

  char* ws = (char*)d_ws;
  unsigned short* Xb = (unsigned short*)(ws);                        // 16 MB
  unsigned short* Wb = (unsigned short*)(ws + (size_t)(16 << 20));   //  2 MB
  unsigned short* XP = (unsigned short*)(ws + (size_t)(18 << 20));   // 16 MB
  float* diag = (float*)(ws + (size_t)(34 << 20));                   // 32 KB
  float* Lrow = (float*)(ws + (size_t)(34 << 20) + 32768);           // 32 KB
  unsigned short* Pb = (unsigned short*)(ws + (size_t)(64 << 20));   // 128 MB bf16 P

  zerok<<<(2 * NR + 255) / 256, 256, 0, stream>>>(diag, 2 * NR);  // diag+Lrow contiguous
  cvt_bf16<<<NR * DIM / 4 / 256, 256, 0, stream>>>(x, Xb, NR * DIM / 4);
  cvt_bf16<<<DIM * DIM / 4 / 256, 256, 0, stream>>>(W, Wb, DIM * DIM / 4);
  gemm1_relu<<<dim3(DIM / 128, NR / 128), 256, 0, stream>>>(Xb, Wb, b, XP, diag);
  gemm2_scores<<<2080, 256, 0, stream>>>(XP, rw, Pb, diag, Lrow);
  normk<<<(NR / 4) * (NR / 256), 256, 0, stream>>>(Pb, out, Lrow);
}